// Round 2
// baseline (1033.058 us; speedup 1.0000x reference)
//
#include <hip/hip_runtime.h>

#define N_NODES 50000
#define N_EDGES 800000

typedef __attribute__((ext_vector_type(8))) short short8;
typedef __attribute__((ext_vector_type(4))) float f32x4;

__device__ inline unsigned short f2b(float f) {
  union { float f; unsigned int u; } c; c.f = f;
  unsigned int u = c.u;
  u += 0x7FFF + ((u >> 16) & 1);   // round-to-nearest-even
  return (unsigned short)(u >> 16);
}
__device__ inline float b2f(unsigned short s) {
  union { unsigned int u; float f; } c; c.u = ((unsigned int)s) << 16;
  return c.f;
}

// ---------------- graph preprocessing ----------------
// edge_index arrives as int32 [2][E]  (harness converts int64 -> int32)

__global__ void k_deg(const int* __restrict__ ei, int* __restrict__ deg) {
  int e = blockIdx.x * 256 + threadIdx.x;
  if (e < N_EDGES) atomicAdd(&deg[ei[N_EDGES + e]], 1);
}

__global__ void k_dinv(const int* __restrict__ deg, float* __restrict__ dinv) {
  int n = blockIdx.x * 256 + threadIdx.x;
  if (n < N_NODES) dinv[n] = rsqrtf((float)(deg[n] + 1));  // +1 self loop
}

// single-block exclusive scan of deg -> rowptr[0..n], rowptr[n]=total
__global__ void k_scan(const int* __restrict__ cnt, int* __restrict__ rowptr, int n) {
  __shared__ int tmp[1024];
  __shared__ int sCarry;
  int tid = threadIdx.x;
  if (tid == 0) sCarry = 0;
  __syncthreads();
  for (int base = 0; base < n; base += 1024) {
    int i = base + tid;
    int v = (i < n) ? cnt[i] : 0;
    tmp[tid] = v;
    __syncthreads();
    for (int off = 1; off < 1024; off <<= 1) {
      int t = (tid >= off) ? tmp[tid - off] : 0;
      __syncthreads();
      tmp[tid] += t;
      __syncthreads();
    }
    if (i < n) rowptr[i] = sCarry + tmp[tid] - v;
    __syncthreads();
    if (tid == 0) sCarry += tmp[1023];
    __syncthreads();
  }
  if (tid == 0) rowptr[n] = sCarry;
}

__global__ void k_fill(const int* __restrict__ ei, const int* __restrict__ rowptr,
                       int* __restrict__ cur, int* __restrict__ csr) {
  int e = blockIdx.x * 256 + threadIdx.x;
  if (e < N_EDGES) {
    int d = ei[N_EDGES + e];
    int p = atomicAdd(&cur[d], 1);
    csr[rowptr[d] + p] = ei[e];
  }
}

// pack head weights [256 x 3075] + biases [3075]
__global__ void k_pack(const float* __restrict__ Wt, const float* __restrict__ Ws,
                       const float* __restrict__ Wf, const float* __restrict__ Wa,
                       const float* __restrict__ bt, const float* __restrict__ bs,
                       const float* __restrict__ bfv, const float* __restrict__ ba,
                       float* __restrict__ Wcat, float* __restrict__ bcat) {
  int idx = blockIdx.x * 256 + threadIdx.x;
  const int total = 256 * 3075;
  if (idx < total) {
    int k = idx / 3075, c = idx - k * 3075;
    float v;
    if (c < 30)      v = Wt[k * 30 + c];
    else if (c < 55) v = Ws[k * 25 + (c - 30)];
    else if (c < 75) v = Wf[k * 20 + (c - 55)];
    else             v = Wa[k * 3000 + (c - 75)];
    Wcat[idx] = v;
  }
  if (idx < 3075) {
    float v;
    if (idx < 30)      v = bt[idx];
    else if (idx < 55) v = bs[idx - 30];
    else if (idx < 75) v = bfv[idx - 55];
    else               v = ba[idx - 75];
    bcat[idx] = v;
  }
}

// ---------------- aggregation (one wave per node) ----------------

// agg1[n] = sum_{e:dst=n} x[src]*dinv[src]*dinv[n] + x[n]*dinv[n]^2  -> bf16
__global__ void k_agg1(const float* __restrict__ x, const float* __restrict__ dinv,
                       const int* __restrict__ rowptr, const int* __restrict__ csr,
                       unsigned short* __restrict__ A1) {
  int n = blockIdx.x;
  int l = threadIdx.x;  // 64 lanes, 2 dims each (128 total)
  float dn = dinv[n];
  const float2* x2 = (const float2*)x;
  float2 xs = x2[(size_t)n * 64 + l];
  float a0 = xs.x * dn * dn, a1 = xs.y * dn * dn;
  int e0 = rowptr[n], e1 = rowptr[n + 1];
  for (int e = e0; e < e1; ++e) {
    int s = csr[e];
    float c = dinv[s] * dn;
    float2 v = x2[(size_t)s * 64 + l];
    a0 += v.x * c; a1 += v.y * c;
  }
  unsigned int pk = (unsigned int)f2b(a0) | ((unsigned int)f2b(a1) << 16);
  ((unsigned int*)A1)[(size_t)n * 64 + l] = pk;
}

// g[n] = sum t[src]*coef + t[n]*dinv^2 + b2 -> bf16   (t is bf16, 256 dims)
__global__ void k_agg2(const unsigned short* __restrict__ t, const float* __restrict__ dinv,
                       const int* __restrict__ rowptr, const int* __restrict__ csr,
                       const float* __restrict__ b2, unsigned short* __restrict__ g) {
  int n = blockIdx.x;
  int l = threadIdx.x;  // 64 lanes, 4 dims each (256 total)
  float dn = dinv[n];
  const ushort4* t4 = (const ushort4*)t;
  ushort4 sv = t4[(size_t)n * 64 + l];
  float a0 = b2f(sv.x) * dn * dn, a1 = b2f(sv.y) * dn * dn;
  float a2 = b2f(sv.z) * dn * dn, a3 = b2f(sv.w) * dn * dn;
  int e0 = rowptr[n], e1 = rowptr[n + 1];
  for (int e = e0; e < e1; ++e) {
    int s = csr[e];
    float c = dinv[s] * dn;
    ushort4 v = t4[(size_t)s * 64 + l];
    a0 += b2f(v.x) * c; a1 += b2f(v.y) * c; a2 += b2f(v.z) * c; a3 += b2f(v.w) * c;
  }
  int d0 = l * 4;
  a0 += b2[d0]; a1 += b2[d0 + 1]; a2 += b2[d0 + 2]; a3 += b2[d0 + 3];
  ushort4 o;
  o.x = f2b(a0); o.y = f2b(a1); o.z = f2b(a2); o.w = f2b(a3);
  ((ushort4*)g)[(size_t)n * 64 + l] = o;
}

// ---------------- bf16 MFMA GEMM ----------------
// A: bf16 [M x K] row-major.  B: f32 [K x N] row-major (converted in staging).
// EPI 0: out bf16 = relu(acc + bias[col])      (ld = N)
// EPI 1: out bf16 = acc                        (ld = N)
// EPI 2: out f32  = acc + bias[col], segmented into the 4 head tensors

#define BM 128
#define BN 128
#define BK 32
#define LDT 40  // ushort row stride (32 + 8 pad -> 80B, 16B-aligned)

template <int EPI>
__global__ __launch_bounds__(256)
void gemm_k(const unsigned short* __restrict__ A, const float* __restrict__ B,
            const float* __restrict__ bias, void* __restrict__ out,
            int M, int K, int N) {
  __shared__ unsigned short lA[BM * LDT];
  __shared__ unsigned short lB[BN * LDT];
  int tid = threadIdx.x;
  int lane = tid & 63, wid = tid >> 6;
  int ln = lane & 15, grp = lane >> 4;
  int wr = wid >> 1, wc = wid & 1;
  int row0 = blockIdx.y * BM, col0 = blockIdx.x * BN;

  f32x4 acc[4][4];
  f32x4 z = {0.f, 0.f, 0.f, 0.f};
#pragma unroll
  for (int m = 0; m < 4; ++m)
#pragma unroll
    for (int n = 0; n < 4; ++n) acc[m][n] = z;

  int cl = tid & 127;      // B staging: col in tile
  int ph = tid >> 7;       // 0..1 -> kpair halves
  int colg = col0 + cl;
  bool colok = colg < N;

  for (int k0 = 0; k0 < K; k0 += BK) {
    // --- stage A: 512 chunks of 8 bf16; chunk c: row=c>>2, quarter=c&3
#pragma unroll
    for (int cc = 0; cc < 2; ++cc) {
      int c = tid + cc * 256;
      int r = c >> 2, q = c & 3;
      int gr = row0 + r;
      uint4 v = {0u, 0u, 0u, 0u};
      if (gr < M) v = *(const uint4*)(A + (size_t)gr * K + k0 + q * 8);
      *(uint4*)(&lA[r * LDT + q * 8]) = v;
    }
    // --- stage B transposed: lB[col][k], f32 -> bf16 packed pairs
#pragma unroll
    for (int i = 0; i < 8; ++i) {
      int p = ph * 8 + i;
      int k = k0 + 2 * p;
      float f0 = 0.f, f1 = 0.f;
      if (colok) {
        f0 = B[(size_t)k * N + colg];
        f1 = B[(size_t)(k + 1) * N + colg];
      }
      unsigned int pk = (unsigned int)f2b(f0) | ((unsigned int)f2b(f1) << 16);
      *(unsigned int*)(&lB[cl * LDT + 2 * p]) = pk;
    }
    __syncthreads();
    short8 af[4], bfr[4];
#pragma unroll
    for (int m = 0; m < 4; ++m)
      af[m] = *(const short8*)(&lA[(wr * 64 + m * 16 + ln) * LDT + grp * 8]);
#pragma unroll
    for (int n = 0; n < 4; ++n)
      bfr[n] = *(const short8*)(&lB[(wc * 64 + n * 16 + ln) * LDT + grp * 8]);
#pragma unroll
    for (int m = 0; m < 4; ++m)
#pragma unroll
      for (int n = 0; n < 4; ++n)
        acc[m][n] = __builtin_amdgcn_mfma_f32_16x16x32_bf16(af[m], bfr[n], acc[m][n], 0, 0, 0);
    __syncthreads();
  }

  // --- epilogue: D frag col=lane&15, row=(lane>>4)*4+r  (verified layout)
#pragma unroll
  for (int m = 0; m < 4; ++m) {
#pragma unroll
    for (int n = 0; n < 4; ++n) {
      int gcn = col0 + wc * 64 + n * 16 + ln;
#pragma unroll
      for (int r = 0; r < 4; ++r) {
        int grow = row0 + wr * 64 + m * 16 + grp * 4 + r;
        if (grow >= M) continue;
        float v = acc[m][n][r];
        if (EPI == 0) {
          v += bias[gcn];
          v = v > 0.f ? v : 0.f;
          ((unsigned short*)out)[(size_t)grow * N + gcn] = f2b(v);
        } else if (EPI == 1) {
          ((unsigned short*)out)[(size_t)grow * N + gcn] = f2b(v);
        } else {
          if (gcn >= N) continue;
          v += bias[gcn];
          float* o = (float*)out;
          size_t off;
          if (gcn < 30)      off = (size_t)grow * 30 + gcn;
          else if (gcn < 55) off = (size_t)N_NODES * 30 + (size_t)grow * 25 + (gcn - 30);
          else if (gcn < 75) off = (size_t)N_NODES * 55 + (size_t)grow * 20 + (gcn - 55);
          else               off = (size_t)N_NODES * 75 + (size_t)grow * 3000 + (gcn - 75);
          o[off] = v;
        }
      }
    }
  }
}

// ---------------- launch ----------------

extern "C" void kernel_launch(void* const* d_in, const int* in_sizes, int n_in,
                              void* d_out, int out_size, void* d_ws, size_t ws_size,
                              hipStream_t stream) {
  const float* x   = (const float*)d_in[0];
  const int* ei    = (const int*)d_in[1];   // int32 [2][E] per harness contract
  const float* W1 = (const float*)d_in[2];
  const float* b1 = (const float*)d_in[3];
  const float* W2 = (const float*)d_in[4];
  const float* b2 = (const float*)d_in[5];
  const float* Wt = (const float*)d_in[6];
  const float* bt = (const float*)d_in[7];
  const float* Ws = (const float*)d_in[8];
  const float* bs = (const float*)d_in[9];
  const float* Wf = (const float*)d_in[10];
  const float* bf_ = (const float*)d_in[11];
  const float* Wa = (const float*)d_in[12];
  const float* ba = (const float*)d_in[13];

  char* ws = (char*)d_ws;
  size_t off = 0;
  auto alloc = [&](size_t bytes) {
    void* p = ws + off;
    off = (off + bytes + 255) & ~(size_t)255;
    return p;
  };
  int* deg    = (int*)alloc(N_NODES * 4);
  int* cur    = (int*)alloc(N_NODES * 4);
  float* dinv = (float*)alloc(N_NODES * 4);
  int* rowptr = (int*)alloc((N_NODES + 1) * 4);
  int* csr    = (int*)alloc((size_t)N_EDGES * 4);
  unsigned short* A1 = (unsigned short*)alloc((size_t)N_NODES * 128 * 2);
  unsigned short* h  = (unsigned short*)alloc((size_t)N_NODES * 512 * 2);
  unsigned short* t  = (unsigned short*)alloc((size_t)N_NODES * 256 * 2);
  unsigned short* g  = h;  // alias: h is dead after gemm1, g written in agg2
  float* Wcat = (float*)alloc((size_t)256 * 3075 * 4);
  float* bcat = (float*)alloc(3075 * 4);

  hipMemsetAsync(deg, 0, N_NODES * 4, stream);
  hipMemsetAsync(cur, 0, N_NODES * 4, stream);
  k_deg<<<(N_EDGES + 255) / 256, 256, 0, stream>>>(ei, deg);
  k_dinv<<<(N_NODES + 255) / 256, 256, 0, stream>>>(deg, dinv);
  k_scan<<<1, 1024, 0, stream>>>(deg, rowptr, N_NODES);
  k_fill<<<(N_EDGES + 255) / 256, 256, 0, stream>>>(ei, rowptr, cur, csr);
  k_pack<<<(256 * 3075 + 255) / 256, 256, 0, stream>>>(Wt, Ws, Wf, Wa, bt, bs, bf_, ba, Wcat, bcat);
  k_agg1<<<N_NODES, 64, 0, stream>>>(x, dinv, rowptr, csr, A1);
  gemm_k<0><<<dim3(4, 391), 256, 0, stream>>>(A1, W1, b1, h, N_NODES, 128, 512);
  gemm_k<1><<<dim3(2, 391), 256, 0, stream>>>(h, W2, nullptr, t, N_NODES, 512, 256);
  k_agg2<<<N_NODES, 64, 0, stream>>>(t, dinv, rowptr, csr, b2, g);
  gemm_k<2><<<dim3(25, 391), 256, 0, stream>>>(g, Wcat, bcat, d_out, N_NODES, 256, 3075);
}